// Round 4
// baseline (375.621 us; speedup 1.0000x reference)
//
#include <hip/hip_runtime.h>
#include <math.h>

#define G  300
#define NS 256
#define NR 4096
#define CT 32        // interleaved texel channels: 0-7 density, 8-31 app
#define SLABS 4      // row-slabs per plane: 75 rows = 1.44 MB -> L2-resident

typedef _Float16 half16_t;
typedef _Float16 h8 __attribute__((ext_vector_type(8)));

// ---------------------------------------------------------------------------
// Prep: interleave density(8ch) + app(24ch) planes into fp16 texels [i][y][x][c].
// Line tail (3*G texels) folded into the same grid.
// ---------------------------------------------------------------------------
__global__ __launch_bounds__(256) void prep_all(
    const float* __restrict__ dp, const float* __restrict__ ap,
    const float* __restrict__ dl, const float* __restrict__ al,
    half16_t* __restrict__ outp, half16_t* __restrict__ outl)
{
  int t = blockIdx.x * blockDim.x + threadIdx.x;
  if (t < 3 * G * G) {
    int x  = t % G;
    int yi = t / G;
    int y  = yi % G;
    int i  = yi / G;
    const float* dpp = dp + ((size_t)(i * 8) * G + y) * G + x;
    const float* app = ap + ((size_t)(i * 24) * G + y) * G + x;
    h8 v[4];
#pragma unroll
    for (int c = 0; c < 8; ++c) v[c >> 3][c & 7] = (half16_t)dpp[(size_t)c * G * G];
#pragma unroll
    for (int c = 0; c < 24; ++c) {
      int cc = c + 8;
      v[cc >> 3][cc & 7] = (half16_t)app[(size_t)c * G * G];
    }
    h8* o = (h8*)(outp + (size_t)t * CT);
#pragma unroll
    for (int m = 0; m < 4; ++m) o[m] = v[m];
  } else {
    int u = t - 3 * G * G;
    if (u < 3 * G) {
      int p = u % G;
      int i = u / G;
      h8 v[4];
#pragma unroll
      for (int c = 0; c < 8; ++c) v[c >> 3][c & 7] = (half16_t)dl[(i * 8 + c) * G + p];
#pragma unroll
      for (int c = 0; c < 24; ++c) {
        int cc = c + 8;
        v[cc >> 3][cc & 7] = (half16_t)al[(i * 24 + c) * G + p];
      }
      h8* o = (h8*)(outl + (size_t)u * CT);
#pragma unroll
      for (int m = 0; m < 4; ++m) o[m] = v[m];
    }
  }
}

// ---------------------------------------------------------------------------
// Main fused kernel — slab-phased gathers.
// Block = 256 threads = 4 waves = 2 rays; each ray split across 2 waves
// (128 samples each). Quartet (4 lanes) per sample, 8 ch/lane (R2 structure —
// fastest measured).
//
// R3 post-mortem: doubling resident waves left delivered L2-miss line rate
// unchanged -> per-CU miss-queue x L3-latency bound. Lever = L2 hit rate.
// So: iterate plane -> slab (75 rows, 1.44 MB) -> samples-in-slab, so all
// blocks' gathers are slab-coherent in time and each XCD L2 holds the live
// slab. Features are additive across planes; partial (sigma,r,g,b) accumulate
// in LDS srgb. Per-sample (fx,fy,ft) precomputed into LDS once.
// ---------------------------------------------------------------------------
__global__ __launch_bounds__(256) void tensorf_fused(
    const float* __restrict__ xyz, const float* __restrict__ zv,
    const half16_t* __restrict__ planes, const half16_t* __restrict__ lns,
    const float* __restrict__ dbw, const float* __restrict__ abw,
    const float* __restrict__ aabb, float* __restrict__ out)
{
  __shared__ float4 srgb[2][NS];       // accumulated (sigma_feat, r, g, b)
  __shared__ float2 sFxy[2][3][NS];    // per ray-slot, plane, sample: (fx, fy)
  __shared__ float  sFt [2][3][NS];    // line coordinate ft
  __shared__ float  sW[3][128];        // [rgb row][c]: c<72 app; 72..95 density mirror
  __shared__ float  sTot[2];
  __shared__ float4 sSum[2][2];

  const int tid = threadIdx.x;
  for (int idx = tid; idx < 3 * 128; idx += 256) {
    int j = idx >> 7, c = idx & 127;
    float v = 0.f;
    if (c < 72) v = abw[j * 72 + c];
    else if (j == 0 && c < 96) v = dbw[c - 72];
    sW[j][c] = v;
  }

  const int wv   = tid >> 6;
  const int lane = tid & 63;
  const int rl   = wv >> 1;              // ray slot within block (0..1)
  const int hf   = wv & 1;               // half of the ray (0..1)
  const int ray  = (blockIdx.x << 1) + rl;
  const int q    = lane >> 2;            // quartet id: sample slot (0..15)
  const int r    = lane & 3;             // channel group (8 ch each)

  const float a0x = aabb[0], a0y = aabb[1], a0z = aabb[2];
  const float ivx = 2.f / (aabb[3] - aabb[0]);
  const float ivy = 2.f / (aabb[4] - aabb[1]);
  const float ivz = 2.f / (aabb[5] - aabb[2]);

  const int MA[3] = {0, 0, 1};   // MAT_MODE first
  const int MB[3] = {1, 2, 2};   // MAT_MODE second
  const int MV[3] = {2, 1, 0};   // VEC_MODE

  const int ro = r * 8;

  // ---- precompute phase: coords to LDS, zero srgb --------------------------
  {
    int sbase = (hf << 7) + (lane << 1);
#pragma unroll
    for (int u = 0; u < 2; ++u) {
      int s = sbase + u;
      const float* xp = xyz + ((size_t)ray * NS + s) * 3;
      float g0 = (xp[0] - a0x) * ivx - 1.f;
      float g1 = (xp[1] - a0y) * ivy - 1.f;
      float g2 = (xp[2] - a0z) * ivz - 1.f;
      float g[3] = {g0, g1, g2};
#pragma unroll
      for (int i = 0; i < 3; ++i) {
        float fx = (g[MA[i]] + 1.f) * (0.5f * (G - 1));
        float fy = (g[MB[i]] + 1.f) * (0.5f * (G - 1));
        float ft = (g[MV[i]] + 1.f) * (0.5f * (G - 1));
        sFxy[rl][i][s] = make_float2(fx, fy);
        sFt [rl][i][s] = ft;
      }
      srgb[rl][s] = make_float4(0.f, 0.f, 0.f, 0.f);
    }
  }
  __syncthreads();

  // ---- gather phase: plane -> slab -> samples ------------------------------
  const float slabInv = (float)SLABS / (float)G;   // slab = floor(fy * SLABS/G)

  for (int p = 0; p < 3; ++p) {
    const half16_t* pb = planes + (size_t)p * G * G * CT;
    const half16_t* lb = lns + (size_t)p * G * CT + ro;
    const int cb = (r == 0) ? (72 + p * 8) : (p * 24 + (r - 1) * 8);

    for (int sl = 0; sl < SLABS; ++sl) {
      for (int it = 0; it < 8; ++it) {
        int s = (hf << 7) + (it << 4) + q;
        float2 fxy = sFxy[rl][p][s];
        int slab = (int)(fxy.y * slabInv);
        if (slab != sl) continue;          // predicated off: ~6 instr overhead

        float ft  = sFt[rl][p][s];
        float x0f = floorf(fxy.x), y0f = floorf(fxy.y), t0f = floorf(ft);
        float wx = fxy.x - x0f, wy = fxy.y - y0f, wt = ft - t0f;
        int x0 = min(max((int)x0f, 0), G - 1);
        int y0 = min(max((int)y0f, 0), G - 1);
        int t0 = min(max((int)t0f, 0), G - 1);
        int x1 = min(x0 + 1, G - 1);
        int y1 = min(y0 + 1, G - 1);
        int t1 = min(t0 + 1, G - 1);

        h8 t00 = *(const h8*)(pb + ((size_t)(y0 * G + x0)) * CT + ro);
        h8 t01 = *(const h8*)(pb + ((size_t)(y0 * G + x1)) * CT + ro);
        h8 t10 = *(const h8*)(pb + ((size_t)(y1 * G + x0)) * CT + ro);
        h8 t11 = *(const h8*)(pb + ((size_t)(y1 * G + x1)) * CT + ro);
        h8 l0  = *(const h8*)(lb + (size_t)t0 * CT);
        h8 l1  = *(const h8*)(lb + (size_t)t1 * CT);

        float w00 = (1.f - wx) * (1.f - wy), w01 = wx * (1.f - wy);
        float w10 = (1.f - wx) * wy,         w11 = wx * wy;
        float wl0 = 1.f - wt;

        float acc0 = 0.f, acc1 = 0.f, acc2 = 0.f;
        {
          const float4* wp0 = (const float4*)&sW[0][cb];
          const float4* wp1 = (const float4*)&sW[1][cb];
          const float4* wp2 = (const float4*)&sW[2][cb];
          float f[8];
#pragma unroll
          for (int k = 0; k < 8; ++k) {
            float pf = (float)t00[k] * w00 + (float)t01[k] * w01
                     + (float)t10[k] * w10 + (float)t11[k] * w11;
            float lf = (float)l0[k] * wl0 + (float)l1[k] * wt;
            f[k] = pf * lf;
          }
          float4 wa, wb;
          wa = wp0[0]; wb = wp0[1];
          acc0 = wa.x * f[0] + wa.y * f[1] + wa.z * f[2] + wa.w * f[3]
               + wb.x * f[4] + wb.y * f[5] + wb.z * f[6] + wb.w * f[7];
          wa = wp1[0]; wb = wp1[1];
          acc1 = wa.x * f[0] + wa.y * f[1] + wa.z * f[2] + wa.w * f[3]
               + wb.x * f[4] + wb.y * f[5] + wb.z * f[6] + wb.w * f[7];
          wa = wp2[0]; wb = wp2[1];
          acc2 = wa.x * f[0] + wa.y * f[1] + wa.z * f[2] + wa.w * f[3]
               + wb.x * f[4] + wb.y * f[5] + wb.z * f[6] + wb.w * f[7];
        }

        // pack (sigma_feat, r, g, b) and reduce across the quartet.
        // All 4 lanes of a quartet share s -> same slab -> no intra-quartet
        // divergence; shuffles stay within the quartet.
        float4 v;
        v.x = (r == 0) ? acc0 : 0.f;
        v.y = (r == 0) ? 0.f : acc0;
        v.z = (r == 0) ? 0.f : acc1;
        v.w = (r == 0) ? 0.f : acc2;
#pragma unroll
        for (int m = 1; m <= 2; m <<= 1) {
          v.x += __shfl_xor(v.x, m);
          v.y += __shfl_xor(v.y, m);
          v.z += __shfl_xor(v.z, m);
          v.w += __shfl_xor(v.w, m);
        }
        if (r == 0) {
          float4 a = srgb[rl][s];
          a.x += v.x; a.y += v.y; a.z += v.z; a.w += v.w;
          srgb[rl][s] = a;
        }
      }
    }
  }
  __syncthreads();

  // ---- transmittance scan. Each wave owns its 128-sample half: 2/lane. ----
  const int s0 = (hf << 7) + (lane << 1);
  const float* zp = zv + (size_t)ray * NS + s0;
  float2 z2 = *(const float2*)zp;
  float d0 = z2.y - z2.x;
  float d1 = (s0 + 2 < NS) ? (zp[2] - z2.y) : d0;   // last sample reuses prev dist

  float4 c0 = srgb[rl][s0];
  float4 c1 = srgb[rl][s0 + 1];

  float vs0 = c0.x - 10.0f;  // DENSITY_SHIFT
  float sp0 = (vs0 > 0.f) ? (vs0 + log1pf(expf(-vs0))) : log1pf(expf(vs0));
  float al0 = 1.f - expf(-sp0 * (d0 * 25.0f));  // DISTANCE_SCALE
  float vs1 = c1.x - 10.0f;
  float sp1 = (vs1 > 0.f) ? (vs1 + log1pf(expf(-vs1))) : log1pf(expf(vs1));
  float al1 = 1.f - expf(-sp1 * (d1 * 25.0f));

  float tl = (1.f - al0 + 1e-10f) * (1.f - al1 + 1e-10f);

  // inclusive prefix product across the wave
  float incl = tl;
#pragma unroll
  for (int off = 1; off < 64; off <<= 1) {
    float pp = __shfl_up(incl, off);
    if (lane >= off) incl *= pp;
  }
  float Twave = __shfl_up(incl, 1);
  if (lane == 0) Twave = 1.f;

  // wave 0 publishes its total transmittance for wave 1 of the same ray
  if (hf == 0 && lane == 63) sTot[rl] = incl;
  __syncthreads();

  float Tstart = hf ? sTot[rl] : 1.f;
  float T = Tstart * Twave;

  float w0 = al0 * T;
  T *= (1.f - al0 + 1e-10f);
  float w1 = al1 * T;

  float ar = w0 * c0.y + w1 * c1.y;
  float ag = w0 * c0.z + w1 * c1.z;
  float ab = w0 * c0.w + w1 * c1.w;
#pragma unroll
  for (int off = 32; off > 0; off >>= 1) {
    ar += __shfl_down(ar, off);
    ag += __shfl_down(ag, off);
    ab += __shfl_down(ab, off);
  }
  if (lane == 0) sSum[rl][hf] = make_float4(ar, ag, ab, 0.f);
  __syncthreads();

  if (hf == 0 && lane == 0) {
    float4 A = sSum[rl][0];
    float4 B = sSum[rl][1];
    out[ray * 3 + 0] = A.x + B.x;
    out[ray * 3 + 1] = A.y + B.y;
    out[ray * 3 + 2] = A.z + B.z;
  }
}

// ---------------------------------------------------------------------------
extern "C" void kernel_launch(void* const* d_in, const int* in_sizes, int n_in,
                              void* d_out, int out_size, void* d_ws, size_t ws_size,
                              hipStream_t stream)
{
  const float* xyz  = (const float*)d_in[0];
  // d_in[1] = viewdirs (unused by reference output path)
  const float* zv   = (const float*)d_in[2];
  const float* dp   = (const float*)d_in[3];
  const float* dl   = (const float*)d_in[4];
  const float* ap   = (const float*)d_in[5];
  const float* al   = (const float*)d_in[6];
  const float* dbw  = (const float*)d_in[7];
  const float* abw  = (const float*)d_in[8];
  const float* aabb = (const float*)d_in[9];
  float* out = (float*)d_out;

  half16_t* planes16 = (half16_t*)d_ws;                    // 3*300*300*32 halves = 17.28 MB
  half16_t* lines16  = planes16 + (size_t)3 * G * G * CT;  // 28800 halves

  hipLaunchKernelGGL(prep_all, dim3((3 * G * G + 3 * G + 255) / 256), dim3(256), 0, stream,
                     dp, ap, dl, al, planes16, lines16);
  hipLaunchKernelGGL(tensorf_fused, dim3(NR / 2), dim3(256), 0, stream,
                     xyz, zv, planes16, lines16, dbw, abw, aabb, out);
}

// Round 7
// 220.151 us; speedup vs baseline: 1.7062x; 1.7062x over previous
//
#include <hip/hip_runtime.h>
#include <math.h>

#define G  300
#define NS 256
#define NR 4096
#define CT 32        // interleaved texel channels: 0-7 density, 8-31 app
#define SLABS 4      // 75 rows/slab = 1.44 MB per plane-slab (fits 4 MB XCD L2)

typedef _Float16 half16_t;
typedef _Float16 h8 __attribute__((ext_vector_type(8)));

// ---------------------------------------------------------------------------
// Prep: interleave density(8ch) + app(24ch) planes into fp16 texels [i][y][x][c].
// Line tail (3*G texels) folded into the same grid.
// ---------------------------------------------------------------------------
__global__ __launch_bounds__(256) void prep_all(
    const float* __restrict__ dp, const float* __restrict__ ap,
    const float* __restrict__ dl, const float* __restrict__ al,
    half16_t* __restrict__ outp, half16_t* __restrict__ outl)
{
  int t = blockIdx.x * blockDim.x + threadIdx.x;
  if (t < 3 * G * G) {
    int x  = t % G;
    int yi = t / G;
    int y  = yi % G;
    int i  = yi / G;
    const float* dpp = dp + ((size_t)(i * 8) * G + y) * G + x;
    const float* app = ap + ((size_t)(i * 24) * G + y) * G + x;
    h8 v[4];
#pragma unroll
    for (int c = 0; c < 8; ++c) v[c >> 3][c & 7] = (half16_t)dpp[(size_t)c * G * G];
#pragma unroll
    for (int c = 0; c < 24; ++c) {
      int cc = c + 8;
      v[cc >> 3][cc & 7] = (half16_t)app[(size_t)c * G * G];
    }
    h8* o = (h8*)(outp + (size_t)t * CT);
#pragma unroll
    for (int m = 0; m < 4; ++m) o[m] = v[m];
  } else {
    int u = t - 3 * G * G;
    if (u < 3 * G) {
      int p = u % G;
      int i = u / G;
      h8 v[4];
#pragma unroll
      for (int c = 0; c < 8; ++c) v[c >> 3][c & 7] = (half16_t)dl[(i * 8 + c) * G + p];
#pragma unroll
      for (int c = 0; c < 24; ++c) {
        int cc = c + 8;
        v[cc >> 3][cc & 7] = (half16_t)al[(i * 24 + c) * G + p];
      }
      h8* o = (h8*)(outl + (size_t)u * CT);
#pragma unroll
      for (int m = 0; m < 4; ++m) o[m] = v[m];
    }
  }
}

// ---------------------------------------------------------------------------
// Main fused kernel — slab-bucketed gathers, ballot binning, REGISTER counts.
//
// Regular launch, 1024 blocks x 256 thr = 4 waves; wave = one full ray.
// Quartet (4 lanes) per sample, 8 ch/lane (r==0: density, r=1..3: app).
//
// R6 post-mortem: garbage loop bound (90 s + 2^18 output) fingerprints the
// LDS count handoff (lane0 ds_write -> all-lane ds_read), not the ballot
// sort (hand-verified). R7: counts stay in registers (ballot popcounts are
// wave-uniform), slab loop fully unrolled (static reg indexing), bound
// clamped to NS by construction, __syncthreads() after lst byte-writes.
// Plane-major gather preserves reference per-sample summation order.
// ---------------------------------------------------------------------------
__global__ __launch_bounds__(256) void tensorf_fused(
    const float* __restrict__ xyz, const float* __restrict__ zv,
    const half16_t* __restrict__ planes, const half16_t* __restrict__ lns,
    const float* __restrict__ dbw, const float* __restrict__ abw,
    const float* __restrict__ aabb, float* __restrict__ out)
{
  __shared__ float4 srgb[4][NS];                    // 16 KB, wave-private
  __shared__ unsigned char lst[4][2][SLABS][NS];    // 8 KB sample-id buckets
  __shared__ float sW[3][128];                      // 1.5 KB basis weights

  const int tid = threadIdx.x;
  for (int idx = tid; idx < 3 * 128; idx += 256) {
    int j = idx >> 7, c = idx & 127;
    float v = 0.f;
    if (c < 72) v = abw[j * 72 + c];
    else if (j == 0 && c < 96) v = dbw[c - 72];
    sW[j][c] = v;
  }

  const int wv   = tid >> 6;
  const int lane = tid & 63;
  const int ray  = (blockIdx.x << 2) + wv;
  const int q    = lane >> 2;            // quartet id (0..15)
  const int r    = lane & 3;             // channel group (8 ch each)

#pragma unroll
  for (int j = 0; j < 4; ++j) srgb[wv][(lane << 2) + j] = make_float4(0.f, 0.f, 0.f, 0.f);

  const float a0x = aabb[0], a0y = aabb[1], a0z = aabb[2];
  const float ivx = 2.f / (aabb[3] - aabb[0]);
  const float ivy = 2.f / (aabb[4] - aabb[1]);
  const float ivz = 2.f / (aabb[5] - aabb[2]);
  const float A0[3] = {a0x, a0y, a0z};
  const float IV[3] = {ivx, ivy, ivz};

  __syncthreads();   // sW visible to all waves

  // ---- binning: deterministic counting sort via ballot rank --------------
  // list 0: plane 0 rows (axis 1); list 1: planes 1,2 rows (axis 2).
  // Counts o0/o1 are wave-uniform (ballot popcounts) and stay in REGISTERS.
  int o0[SLABS] = {0, 0, 0, 0};
  int o1[SLABS] = {0, 0, 0, 0};
  {
    const float slabScale = (float)SLABS / (float)G;
    int key0[4], key1[4];
#pragma unroll
    for (int j = 0; j < 4; ++j) {
      int s = (lane << 2) + j;
      const float* xp = xyz + ((size_t)ray * NS + s) * 3;
      float g1 = (xp[1] - a0y) * ivy - 1.f;
      float g2 = (xp[2] - a0z) * ivz - 1.f;
      float fy0 = (g1 + 1.f) * (0.5f * (G - 1));
      float fy1 = (g2 + 1.f) * (0.5f * (G - 1));
      key0[j] = min(max((int)(fy0 * slabScale), 0), SLABS - 1);
      key1[j] = min(max((int)(fy1 * slabScale), 0), SLABS - 1);
    }
    const unsigned long long ltmask = (1ull << lane) - 1ull;
#pragma unroll
    for (int j = 0; j < 4; ++j) {
      int s = (lane << 2) + j;
#pragma unroll
      for (int k = 0; k < SLABS; ++k) {
        unsigned long long m0 = __ballot(key0[j] == k);
        if (key0[j] == k)
          lst[wv][0][k][o0[k] + __popcll(m0 & ltmask)] = (unsigned char)s;
        o0[k] += (int)__popcll(m0);
        unsigned long long m1 = __ballot(key1[j] == k);
        if (key1[j] == k)
          lst[wv][1][k][o1[k] + __popcll(m1 & ltmask)] = (unsigned char)s;
        o1[k] += (int)__popcll(m1);
      }
    }
  }
  __syncthreads();   // lst byte-writes visible (belt and suspenders)

  const int MA[3] = {0, 0, 1};   // MAT_MODE first
  const int MB[3] = {1, 2, 2};   // MAT_MODE second
  const int MV[3] = {2, 1, 0};   // VEC_MODE
  const int ro = r * 8;

  // ---- gather: plane-major (ref numerics order), slab-phased, dense ------
#pragma unroll
  for (int p = 0; p < 3; ++p) {
    const int li = (p == 0) ? 0 : 1;
    const half16_t* pb = planes + (size_t)p * G * G * CT;
    const half16_t* lb = lns + (size_t)p * G * CT + ro;
    const int cb = (r == 0) ? (72 + p * 8) : (p * 24 + (r - 1) * 8);
    const float4 W0a = *(const float4*)&sW[0][cb];
    const float4 W0b = *(const float4*)&sW[0][cb + 4];
    const float4 W1a = *(const float4*)&sW[1][cb];
    const float4 W1b = *(const float4*)&sW[1][cb + 4];
    const float4 W2a = *(const float4*)&sW[2][cb];
    const float4 W2b = *(const float4*)&sW[2][cb + 4];

#pragma unroll
    for (int sl = 0; sl < SLABS; ++sl) {
      // counts from registers, statically indexed; bound by construction <=256
      const int n = min((li == 0) ? o0[sl] : o1[sl], NS);
      for (int base = 0; base < n; base += 16) {
        int e = base + q;
        if (e < n) {                       // uniform across the quartet
          int sid = lst[wv][li][sl][e];
          const float* xp = xyz + ((size_t)ray * NS + sid) * 3;
          float ga = (xp[MA[p]] - A0[MA[p]]) * IV[MA[p]] - 1.f;
          float gb = (xp[MB[p]] - A0[MB[p]]) * IV[MB[p]] - 1.f;
          float gv = (xp[MV[p]] - A0[MV[p]]) * IV[MV[p]] - 1.f;
          float fx = (ga + 1.f) * (0.5f * (G - 1));
          float fy = (gb + 1.f) * (0.5f * (G - 1));
          float ft = (gv + 1.f) * (0.5f * (G - 1));

          float x0f = floorf(fx), y0f = floorf(fy), t0f = floorf(ft);
          float wx = fx - x0f, wy = fy - y0f, wt = ft - t0f;
          int x0 = min(max((int)x0f, 0), G - 1);
          int y0 = min(max((int)y0f, 0), G - 1);
          int t0 = min(max((int)t0f, 0), G - 1);
          int x1 = min(x0 + 1, G - 1);
          int y1 = min(y0 + 1, G - 1);
          int t1 = min(t0 + 1, G - 1);

          h8 t00 = *(const h8*)(pb + ((size_t)(y0 * G + x0)) * CT + ro);
          h8 t01 = *(const h8*)(pb + ((size_t)(y0 * G + x1)) * CT + ro);
          h8 t10 = *(const h8*)(pb + ((size_t)(y1 * G + x0)) * CT + ro);
          h8 t11 = *(const h8*)(pb + ((size_t)(y1 * G + x1)) * CT + ro);
          h8 l0  = *(const h8*)(lb + (size_t)t0 * CT);
          h8 l1  = *(const h8*)(lb + (size_t)t1 * CT);

          float w00 = (1.f - wx) * (1.f - wy), w01 = wx * (1.f - wy);
          float w10 = (1.f - wx) * wy,         w11 = wx * wy;
          float wl0 = 1.f - wt;

          float f[8];
#pragma unroll
          for (int k = 0; k < 8; ++k) {
            float pf = (float)t00[k] * w00 + (float)t01[k] * w01
                     + (float)t10[k] * w10 + (float)t11[k] * w11;
            float lf = (float)l0[k] * wl0 + (float)l1[k] * wt;
            f[k] = pf * lf;
          }
          float acc0 = W0a.x * f[0] + W0a.y * f[1] + W0a.z * f[2] + W0a.w * f[3]
                     + W0b.x * f[4] + W0b.y * f[5] + W0b.z * f[6] + W0b.w * f[7];
          float acc1 = W1a.x * f[0] + W1a.y * f[1] + W1a.z * f[2] + W1a.w * f[3]
                     + W1b.x * f[4] + W1b.y * f[5] + W1b.z * f[6] + W1b.w * f[7];
          float acc2 = W2a.x * f[0] + W2a.y * f[1] + W2a.z * f[2] + W2a.w * f[3]
                     + W2b.x * f[4] + W2b.y * f[5] + W2b.z * f[6] + W2b.w * f[7];

          // pack (sigma_feat, r, g, b); reduce across the quartet
          float4 v;
          v.x = (r == 0) ? acc0 : 0.f;
          v.y = (r == 0) ? 0.f : acc0;
          v.z = (r == 0) ? 0.f : acc1;
          v.w = (r == 0) ? 0.f : acc2;
#pragma unroll
          for (int m = 1; m <= 2; m <<= 1) {
            v.x += __shfl_xor(v.x, m);
            v.y += __shfl_xor(v.y, m);
            v.z += __shfl_xor(v.z, m);
            v.w += __shfl_xor(v.w, m);
          }
          if (r == 0) {
            float4 a = srgb[wv][sid];
            a.x += v.x; a.y += v.y; a.z += v.z; a.w += v.w;
            srgb[wv][sid] = a;
          }
        }
      }
    }
  }

  // ---- per-ray transmittance scan: lane handles samples lane*4 .. +3 ------
  const float* zp = zv + (size_t)ray * NS + (lane << 2);
  float4 z4 = *(const float4*)zp;
  float znext = __shfl_down(z4.x, 1);
  float d[4];
  d[0] = z4.y - z4.x;
  d[1] = z4.z - z4.y;
  d[2] = z4.w - z4.z;
  d[3] = (lane == 63) ? d[2] : (znext - z4.w);

  float4 c[4];
  float al[4];
  float tl = 1.f;
#pragma unroll
  for (int j = 0; j < 4; ++j) {
    c[j] = srgb[wv][(lane << 2) + j];
    float vs = c[j].x - 10.0f;  // DENSITY_SHIFT
    float sp = (vs > 0.f) ? (vs + log1pf(expf(-vs))) : log1pf(expf(vs));
    al[j] = 1.f - expf(-sp * (d[j] * 25.0f));  // DISTANCE_SCALE
    tl *= (1.f - al[j] + 1e-10f);
  }
  float incl = tl;
#pragma unroll
  for (int off = 1; off < 64; off <<= 1) {
    float pp = __shfl_up(incl, off);
    if (lane >= off) incl *= pp;
  }
  float T = __shfl_up(incl, 1);
  if (lane == 0) T = 1.f;

  float ar = 0.f, ag = 0.f, ab = 0.f;
#pragma unroll
  for (int j = 0; j < 4; ++j) {
    float w = al[j] * T;
    ar += w * c[j].y;
    ag += w * c[j].z;
    ab += w * c[j].w;
    T *= (1.f - al[j] + 1e-10f);
  }
#pragma unroll
  for (int off = 32; off > 0; off >>= 1) {
    ar += __shfl_down(ar, off);
    ag += __shfl_down(ag, off);
    ab += __shfl_down(ab, off);
  }
  if (lane == 0) {
    out[ray * 3 + 0] = ar;
    out[ray * 3 + 1] = ag;
    out[ray * 3 + 2] = ab;
  }
}

// ---------------------------------------------------------------------------
extern "C" void kernel_launch(void* const* d_in, const int* in_sizes, int n_in,
                              void* d_out, int out_size, void* d_ws, size_t ws_size,
                              hipStream_t stream)
{
  const float* xyz  = (const float*)d_in[0];
  // d_in[1] = viewdirs (unused by reference output path)
  const float* zv   = (const float*)d_in[2];
  const float* dp   = (const float*)d_in[3];
  const float* dl   = (const float*)d_in[4];
  const float* ap   = (const float*)d_in[5];
  const float* al   = (const float*)d_in[6];
  const float* dbw  = (const float*)d_in[7];
  const float* abw  = (const float*)d_in[8];
  const float* aabb = (const float*)d_in[9];
  float* outp = (float*)d_out;

  half16_t* planes16 = (half16_t*)d_ws;                    // 3*300*300*32 halves = 17.28 MB
  half16_t* lines16  = planes16 + (size_t)3 * G * G * CT;  // 28800 halves

  hipLaunchKernelGGL(prep_all, dim3((3 * G * G + 3 * G + 255) / 256), dim3(256), 0, stream,
                     dp, ap, dl, al, planes16, lines16);
  hipLaunchKernelGGL(tensorf_fused, dim3(NR / 4), dim3(256), 0, stream,
                     xyz, zv, planes16, lines16, dbw, abw, aabb, outp);
}

// Round 8
// 213.698 us; speedup vs baseline: 1.7577x; 1.0302x over previous
//
#include <hip/hip_runtime.h>
#include <math.h>

#define G  300
#define NS 256
#define NR 4096
#define CT 32        // interleaved texel channels: 0-7 density, 8-31 app
#define SLABS 6      // row-slabs per axis: 50 rows = 0.96 MB; live set 3 slabs = 2.9 MB

typedef _Float16 half16_t;
typedef _Float16 h8 __attribute__((ext_vector_type(8)));

// ---------------------------------------------------------------------------
// Prep: interleave density(8ch) + app(24ch) planes into fp16 texels [i][y][x][c].
// Line tail (3*G texels) folded into the same grid.
// ---------------------------------------------------------------------------
__global__ __launch_bounds__(256) void prep_all(
    const float* __restrict__ dp, const float* __restrict__ ap,
    const float* __restrict__ dl, const float* __restrict__ al,
    half16_t* __restrict__ outp, half16_t* __restrict__ outl)
{
  int t = blockIdx.x * blockDim.x + threadIdx.x;
  if (t < 3 * G * G) {
    int x  = t % G;
    int yi = t / G;
    int y  = yi % G;
    int i  = yi / G;
    const float* dpp = dp + ((size_t)(i * 8) * G + y) * G + x;
    const float* app = ap + ((size_t)(i * 24) * G + y) * G + x;
    h8 v[4];
#pragma unroll
    for (int c = 0; c < 8; ++c) v[c >> 3][c & 7] = (half16_t)dpp[(size_t)c * G * G];
#pragma unroll
    for (int c = 0; c < 24; ++c) {
      int cc = c + 8;
      v[cc >> 3][cc & 7] = (half16_t)app[(size_t)c * G * G];
    }
    h8* o = (h8*)(outp + (size_t)t * CT);
#pragma unroll
    for (int m = 0; m < 4; ++m) o[m] = v[m];
  } else {
    int u = t - 3 * G * G;
    if (u < 3 * G) {
      int p = u % G;
      int i = u / G;
      h8 v[4];
#pragma unroll
      for (int c = 0; c < 8; ++c) v[c >> 3][c & 7] = (half16_t)dl[(i * 8 + c) * G + p];
#pragma unroll
      for (int c = 0; c < 24; ++c) {
        int cc = c + 8;
        v[cc >> 3][cc & 7] = (half16_t)al[(i * 24 + c) * G + p];
      }
      h8* o = (h8*)(outl + (size_t)u * CT);
#pragma unroll
      for (int m = 0; m < 4; ++m) o[m] = v[m];
    }
  }
}

// ---------------------------------------------------------------------------
// Main fused kernel — R0 single-visit body, samples swept in slab-sorted order.
//
// 1024 blocks x 256 thr = 4 waves; wave = one full ray. Quartet (4 lanes)
// per sample, 8 ch/lane (r==0: density, r=1..3: app).
//
// R7 post-mortem: FETCH 461->283 MB but dur -4% — miss volume isn't the
// limiter; the per-plane bucket structure tripled per-sample overhead
// (VALUBusy 38->60%). R8: sort sample ids ONCE by joint slab key
// (k0 = plane0 row-slab [axis1], k1 = planes1/2 row-slab [axis2]); gather is
// R0's exact all-3-planes-per-sample body over the sorted array — 16 fully
// dense iterations, one pack/shuffle/store per sample, no RMW, no guards.
// Sort: ballot counting sort with ONE wave-uniform running offset register
// (R6's LDS-count handoff bug class structurally impossible).
// g[3] computed once at binning, parked in LDS (kills 9M xyz re-reads).
// Per-sample FMA order identical to R0 -> expect bitwise-equal output.
// ---------------------------------------------------------------------------
__global__ __launch_bounds__(256) void tensorf_fused(
    const float* __restrict__ xyz, const float* __restrict__ zv,
    const half16_t* __restrict__ planes, const half16_t* __restrict__ lns,
    const float* __restrict__ dbw, const float* __restrict__ abw,
    const float* __restrict__ aabb, float* __restrict__ out)
{
  __shared__ float4 srgb[4][NS];       // 16 KB, wave-private (sigma,r,g,b)
  __shared__ float4 sG[4][NS];         // 16 KB, wave-private grid coords (g0,g1,g2,-)
  __shared__ unsigned char lst[4][NS]; // 1 KB, slab-sorted sample ids
  __shared__ float sW[3][128];         // 1.5 KB basis weights

  const int tid = threadIdx.x;
  for (int idx = tid; idx < 3 * 128; idx += 256) {
    int j = idx >> 7, c = idx & 127;
    float v = 0.f;
    if (c < 72) v = abw[j * 72 + c];
    else if (j == 0 && c < 96) v = dbw[c - 72];
    sW[j][c] = v;
  }

  const int wv   = tid >> 6;
  const int lane = tid & 63;
  const int ray  = (blockIdx.x << 2) + wv;
  const int q    = lane >> 2;            // quartet id (0..15)
  const int r    = lane & 3;             // channel group (8 ch each)

  const float a0x = aabb[0], a0y = aabb[1], a0z = aabb[2];
  const float ivx = 2.f / (aabb[3] - aabb[0]);
  const float ivy = 2.f / (aabb[4] - aabb[1]);
  const float ivz = 2.f / (aabb[5] - aabb[2]);

  // ---- binning pass: grid coords to LDS once; joint slab key per sample ---
  int key[4];
  {
    const float slabScale = (float)SLABS / (float)G;
#pragma unroll
    for (int j = 0; j < 4; ++j) {
      int s = (lane << 2) + j;
      const float* xp = xyz + ((size_t)ray * NS + s) * 3;
      float g0 = (xp[0] - a0x) * ivx - 1.f;
      float g1 = (xp[1] - a0y) * ivy - 1.f;
      float g2 = (xp[2] - a0z) * ivz - 1.f;
      sG[wv][s] = make_float4(g0, g1, g2, 0.f);
      float fy0 = (g1 + 1.f) * (0.5f * (G - 1));   // plane 0 row coord (axis 1)
      float fy1 = (g2 + 1.f) * (0.5f * (G - 1));   // planes 1,2 row coord (axis 2)
      int k0 = min(max((int)(fy0 * slabScale), 0), SLABS - 1);
      int k1 = min(max((int)(fy1 * slabScale), 0), SLABS - 1);
      key[j] = k0 * SLABS + k1;
    }
  }

  // ---- counting sort by key: single wave-uniform running offset -----------
  {
    const unsigned long long ltmask = (1ull << lane) - 1ull;
    int off = 0;
    for (int b = 0; b < SLABS * SLABS; ++b) {
#pragma unroll
      for (int j = 0; j < 4; ++j) {
        bool hit = (key[j] == b);
        unsigned long long m = __ballot(hit);
        if (hit) lst[wv][off + (int)__popcll(m & ltmask)] =
                   (unsigned char)((lane << 2) + j);
        off += (int)__popcll(m);
      }
    }
  }
  __syncthreads();   // sW (cross-wave) + lst/sG ordering

  const int MA[3] = {0, 0, 1};   // MAT_MODE first
  const int MB[3] = {1, 2, 2};   // MAT_MODE second
  const int MV[3] = {2, 1, 0};   // VEC_MODE
  const int ro = r * 8;

  // ---- gather: dense sweep in sorted order, R0 body -----------------------
  for (int base = 0; base < NS; base += 16) {
    int sid = lst[wv][base + q];
    float4 g4 = sG[wv][sid];
    float g[3] = {g4.x, g4.y, g4.z};

    float acc0 = 0.f, acc1 = 0.f, acc2 = 0.f;
#pragma unroll
    for (int i = 0; i < 3; ++i) {
      float fx = (g[MA[i]] + 1.f) * (0.5f * (G - 1));
      float fy = (g[MB[i]] + 1.f) * (0.5f * (G - 1));
      float ft = (g[MV[i]] + 1.f) * (0.5f * (G - 1));
      float x0f = floorf(fx), y0f = floorf(fy), t0f = floorf(ft);
      float wx = fx - x0f, wy = fy - y0f, wt = ft - t0f;
      int x0 = min(max((int)x0f, 0), G - 1);
      int y0 = min(max((int)y0f, 0), G - 1);
      int t0 = min(max((int)t0f, 0), G - 1);
      int x1 = min(x0 + 1, G - 1);
      int y1 = min(y0 + 1, G - 1);
      int t1 = min(t0 + 1, G - 1);

      const half16_t* pb = planes + (size_t)i * G * G * CT;
      h8 t00 = *(const h8*)(pb + ((size_t)(y0 * G + x0)) * CT + ro);
      h8 t01 = *(const h8*)(pb + ((size_t)(y0 * G + x1)) * CT + ro);
      h8 t10 = *(const h8*)(pb + ((size_t)(y1 * G + x0)) * CT + ro);
      h8 t11 = *(const h8*)(pb + ((size_t)(y1 * G + x1)) * CT + ro);
      const half16_t* lb = lns + (size_t)i * G * CT + ro;
      h8 l0 = *(const h8*)(lb + (size_t)t0 * CT);
      h8 l1 = *(const h8*)(lb + (size_t)t1 * CT);

      float w00 = (1.f - wx) * (1.f - wy), w01 = wx * (1.f - wy);
      float w10 = (1.f - wx) * wy,         w11 = wx * wy;
      float wl0 = 1.f - wt;

      float f[8];
#pragma unroll
      for (int k = 0; k < 8; ++k) {
        float pf = (float)t00[k] * w00 + (float)t01[k] * w01
                 + (float)t10[k] * w10 + (float)t11[k] * w11;
        float lf = (float)l0[k] * wl0 + (float)l1[k] * wt;
        f[k] = pf * lf;
      }

      int cb = (r == 0) ? (72 + i * 8) : (i * 24 + (r - 1) * 8);
      const float4* wp0 = (const float4*)&sW[0][cb];
      const float4* wp1 = (const float4*)&sW[1][cb];
      const float4* wp2 = (const float4*)&sW[2][cb];
      float4 wa, wb;
      wa = wp0[0]; wb = wp0[1];
      acc0 += wa.x * f[0] + wa.y * f[1] + wa.z * f[2] + wa.w * f[3]
            + wb.x * f[4] + wb.y * f[5] + wb.z * f[6] + wb.w * f[7];
      wa = wp1[0]; wb = wp1[1];
      acc1 += wa.x * f[0] + wa.y * f[1] + wa.z * f[2] + wa.w * f[3]
            + wb.x * f[4] + wb.y * f[5] + wb.z * f[6] + wb.w * f[7];
      wa = wp2[0]; wb = wp2[1];
      acc2 += wa.x * f[0] + wa.y * f[1] + wa.z * f[2] + wa.w * f[3]
            + wb.x * f[4] + wb.y * f[5] + wb.z * f[6] + wb.w * f[7];
    }

    // pack (sigma_feat, r, g, b) and reduce across the quartet
    float4 v;
    v.x = (r == 0) ? acc0 : 0.f;
    v.y = (r == 0) ? 0.f : acc0;
    v.z = (r == 0) ? 0.f : acc1;
    v.w = (r == 0) ? 0.f : acc2;
#pragma unroll
    for (int m = 1; m <= 2; m <<= 1) {
      v.x += __shfl_xor(v.x, m);
      v.y += __shfl_xor(v.y, m);
      v.z += __shfl_xor(v.z, m);
      v.w += __shfl_xor(v.w, m);
    }
    if (r == 0) srgb[wv][sid] = v;   // each sample written exactly once
  }
  __syncthreads();

  // ---- per-ray transmittance scan: lane handles samples lane*4 .. +3 ------
  const float* zp = zv + (size_t)ray * NS + (lane << 2);
  float4 z4 = *(const float4*)zp;
  float znext = __shfl_down(z4.x, 1);
  float d[4];
  d[0] = z4.y - z4.x;
  d[1] = z4.z - z4.y;
  d[2] = z4.w - z4.z;
  d[3] = (lane == 63) ? d[2] : (znext - z4.w);

  float4 c[4];
  float al[4];
  float tl = 1.f;
#pragma unroll
  for (int j = 0; j < 4; ++j) {
    c[j] = srgb[wv][(lane << 2) + j];
    float vs = c[j].x - 10.0f;  // DENSITY_SHIFT
    float sp = (vs > 0.f) ? (vs + log1pf(expf(-vs))) : log1pf(expf(vs));
    al[j] = 1.f - expf(-sp * (d[j] * 25.0f));  // DISTANCE_SCALE
    tl *= (1.f - al[j] + 1e-10f);
  }
  float incl = tl;
#pragma unroll
  for (int off = 1; off < 64; off <<= 1) {
    float pp = __shfl_up(incl, off);
    if (lane >= off) incl *= pp;
  }
  float T = __shfl_up(incl, 1);
  if (lane == 0) T = 1.f;

  float ar = 0.f, ag = 0.f, ab = 0.f;
#pragma unroll
  for (int j = 0; j < 4; ++j) {
    float w = al[j] * T;
    ar += w * c[j].y;
    ag += w * c[j].z;
    ab += w * c[j].w;
    T *= (1.f - al[j] + 1e-10f);
  }
#pragma unroll
  for (int off = 32; off > 0; off >>= 1) {
    ar += __shfl_down(ar, off);
    ag += __shfl_down(ag, off);
    ab += __shfl_down(ab, off);
  }
  if (lane == 0) {
    out[ray * 3 + 0] = ar;
    out[ray * 3 + 1] = ag;
    out[ray * 3 + 2] = ab;
  }
}

// ---------------------------------------------------------------------------
extern "C" void kernel_launch(void* const* d_in, const int* in_sizes, int n_in,
                              void* d_out, int out_size, void* d_ws, size_t ws_size,
                              hipStream_t stream)
{
  const float* xyz  = (const float*)d_in[0];
  // d_in[1] = viewdirs (unused by reference output path)
  const float* zv   = (const float*)d_in[2];
  const float* dp   = (const float*)d_in[3];
  const float* dl   = (const float*)d_in[4];
  const float* ap   = (const float*)d_in[5];
  const float* al   = (const float*)d_in[6];
  const float* dbw  = (const float*)d_in[7];
  const float* abw  = (const float*)d_in[8];
  const float* aabb = (const float*)d_in[9];
  float* outp = (float*)d_out;

  half16_t* planes16 = (half16_t*)d_ws;                    // 3*300*300*32 halves = 17.28 MB
  half16_t* lines16  = planes16 + (size_t)3 * G * G * CT;  // 28800 halves

  hipLaunchKernelGGL(prep_all, dim3((3 * G * G + 3 * G + 255) / 256), dim3(256), 0, stream,
                     dp, ap, dl, al, planes16, lines16);
  hipLaunchKernelGGL(tensorf_fused, dim3(NR / 4), dim3(256), 0, stream,
                     xyz, zv, planes16, lines16, dbw, abw, aabb, outp);
}